// Round 6
// baseline (972.901 us; speedup 1.0000x reference)
//
#include <hip/hip_runtime.h>
#include <math.h>

#define NN 50000
#define NF 63
#define NE 800000
#define NL 10000
#define NB 4
#define NLAY 5
#define BN (NB*NN)                 // 200000 rows
#define RPB 32                     // rows per block
#define NPB 8                      // nodes per block
#define NT2 (BN/RPB)               // 6250 blocks
#define SCAN_NBLK ((NN+255)/256)   // 196
#define HIST_NBLK ((NE+255)/256)   // 3125
#define X0_NBLK ((BN*16)/256)      // 12500
#define COV_NBLK ((NB*NL+255)/256) // 157

using f32x4  = __attribute__((ext_vector_type(4))) float;
using f32x2  = __attribute__((ext_vector_type(2))) float;
using bf16x8 = __attribute__((ext_vector_type(8))) __bf16;

__device__ __forceinline__ float frcp(float x){ return __builtin_amdgcn_rcpf(x); }
__device__ __forceinline__ float sigm(float v){ return frcp(1.f + __expf(-v)); }
__device__ __forceinline__ float tanh_f(float v){ return fmaf(-2.f, frcp(__expf(2.f*v) + 1.f), 1.f); }

__device__ __forceinline__ ushort f2bf(float f){
    uint u = __builtin_bit_cast(uint, f);
    u += 0x7fffu + ((u >> 16) & 1u);
    return (ushort)(u >> 16);
}
__device__ __forceinline__ float bf_lo(uint v){ return __builtin_bit_cast(float, v << 16); }
__device__ __forceinline__ float bfu(ushort v){ return __builtin_bit_cast(float, ((uint)v) << 16); }

__device__ __forceinline__ uchar f2fp8(float v){
    int enc = __builtin_amdgcn_cvt_pk_fp8_f32(v, v, 0, false);
    return (uchar)(enc & 0xff);
}

__device__ __forceinline__ bf16x8 ldfrag(const ushort* p){
    uint4 v = *(const uint4*)p;
    return __builtin_bit_cast(bf16x8, v);
}
__device__ __forceinline__ f32x4 MFMA(bf16x8 a, bf16x8 b, f32x4 c){
    return __builtin_amdgcn_mfma_f32_16x16x32_bf16(a, b, c, 0, 0, 0);
}

// ---------------- hist + weight prep + x0 build (merged) ----------------
__global__ void k_setup(const int* __restrict__ edges, int* __restrict__ cnt,
                        const float* __restrict__ wih, const float* __restrict__ whh,
                        const float* __restrict__ aiw, const float* __restrict__ ajw,
                        const float* __restrict__ ggc,
                        ushort* __restrict__ whhb, ushort* __restrict__ aiwb,
                        ushort* __restrict__ ajwb, ushort* __restrict__ wfb,
                        const float* __restrict__ nodes, ushort* __restrict__ x0I,
                        uchar* __restrict__ x0F){
    int bid = blockIdx.x;
    if (bid < HIST_NBLK){
        int e = bid*256 + threadIdx.x;
        if (e < NE) atomicAdd(&cnt[edges[NE + e]], 1);
        return;
    }
    if (bid < HIST_NBLK + 416){
        int i = (bid - HIST_NBLK)*256 + threadIdx.x;   // 0..106495
        if (i < 12288)        whhb[i]        = f2bf(whh[i]);
        else if (i < 28672)   aiwb[i-12288]  = f2bf(aiw[i-12288]);
        else if (i < 45056)   ajwb[i-28672]  = f2bf(ajw[i-28672]);
        else if (i < 106496){
            int t = i - 45056;                         // 0..61439
            int lay = t / 12288;
            int rem = t % 12288;
            int n = rem >> 6, k = rem & 63;
            const float* W  = ggc + lay*4096 + k*64;
            const float* wr = wih + n*64;
            float s = 0.f;
            #pragma unroll 8
            for (int c = 0; c < 64; ++c) s = fmaf(W[c], wr[c], s);
            wfb[t] = f2bf(s);
        }
        return;
    }
    // x0 build: interleaved x0I (bf16) + batch-invariant x0F (fp8)
    int f = (bid - HIST_NBLK - 416)*256 + threadIdx.x; // 8B group index, BN*16 total
    int row = f >> 4, c4 = f & 15;
    int n = row % NN, b = row / NN;
    float v[4];
    #pragma unroll
    for (int i = 0; i < 4; ++i){
        int c = c4*4 + i;
        v[i] = (c < NF) ? nodes[(size_t)n*NF + c] : 0.f;
    }
    uint2 pk;
    pk.x = (uint)f2bf(v[0]) | ((uint)f2bf(v[1]) << 16);
    pk.y = (uint)f2bf(v[2]) | ((uint)f2bf(v[3]) << 16);
    *(uint2*)(x0I + ((size_t)n*4 + b)*64 + c4*4) = pk;
    if (b == 0){
        uint q = 0;
        q = (uint)__builtin_amdgcn_cvt_pk_fp8_f32(v[0], v[1], (int)q, false);
        q = (uint)__builtin_amdgcn_cvt_pk_fp8_f32(v[2], v[3], (int)q, true);
        *(uint*)(x0F + (size_t)n*64 + c4*4) = q;   // col63 stays 0 (v[3]=0 at c4=15)
    }
}

// scan1 + cov scatter (merged; cov blocks don't touch scan state)
__global__ void k_scan1(const int* __restrict__ cnt, int* __restrict__ tmp, int* __restrict__ bsum,
                        const float* __restrict__ cov, const int* __restrict__ c2l,
                        ushort* __restrict__ x0I, ushort* __restrict__ covB){
    if (blockIdx.x >= SCAN_NBLK){
        int i = (blockIdx.x - SCAN_NBLK)*256 + threadIdx.x;
        if (i < NB*NL){
            int b = i / NL, j = i % NL;
            int nd = c2l[j];
            ushort vb = f2bf(cov[i]);
            x0I[((size_t)nd*4 + b)*64 + 63] = vb;
            covB[(size_t)nd*4 + b] = vb;
        }
        return;
    }
    __shared__ int sh[256];
    int tx = threadIdx.x, i = blockIdx.x*256 + tx;
    int v = (i < NN) ? cnt[i] : 0;
    sh[tx] = v; __syncthreads();
    for (int off = 1; off < 256; off <<= 1){
        int u = (tx >= off) ? sh[tx-off] : 0;
        __syncthreads();
        sh[tx] += u;
        __syncthreads();
    }
    int incl = sh[tx];
    if (i < NN) tmp[i] = incl - v;
    if (tx == 255) bsum[blockIdx.x] = incl;
}

// scan of bsum done redundantly per block (merged scan2+scan3)
__global__ void k_scan3(const int* __restrict__ tmp, const int* __restrict__ bsum,
                        int* __restrict__ row_start, int* __restrict__ cursor){
    __shared__ int sh[256];
    int tx = threadIdx.x;
    int v = (tx < SCAN_NBLK) ? bsum[tx] : 0;
    sh[tx] = v; __syncthreads();
    for (int off = 1; off < 256; off <<= 1){
        int u = (tx >= off) ? sh[tx-off] : 0;
        __syncthreads();
        sh[tx] += u;
        __syncthreads();
    }
    int boff = sh[blockIdx.x] - bsum[blockIdx.x];   // exclusive prefix for this block
    int i = blockIdx.x*256 + tx;
    if (i < NN){
        int rs = tmp[i] + boff;
        row_start[i] = rs;
        cursor[i] = rs;
    }
    if (i == 0) row_start[NN] = NE;
}

__global__ void k_fillcsr(const int* __restrict__ edges, int* __restrict__ cursor, int* __restrict__ csr_src){
    int e = blockIdx.x*256 + threadIdx.x;
    if (e < NE){
        int d = edges[NE + e];
        int pos = atomicAdd(&cursor[d], 1);
        csr_src[pos] = edges[e];
    }
}

// ---------------- layer-0 gather: qw-pair per node, 8-deep chunks stride 16, 64B records + cov ----------------
__device__ __forceinline__ void gather0q(const uchar* __restrict__ x0F,
                                         const ushort* __restrict__ covB,
                                         const int* __restrict__ csr_src,
                                         int e0, int e1, int l,
                                         ushort* __restrict__ sAgg, int nodeRow){
    const int h = (l >> 4) & 1;         // which half of the qw pair
    const int t = l & 15;
    const uint off = (uint)(t*4);
    f32x2 a01 = (f32x2){0.f,0.f}, a23 = (f32x2){0.f,0.f};
    float c = 0.f;
    for (int eb = e0 + 8*h; eb < e1; eb += 16){
        int s[8];
        #pragma unroll
        for (int j = 0; j < 8; ++j){ int ee = eb + j; if (ee >= e1) ee = e1 - 1; s[j] = csr_src[ee]; }
        uint v[8];
        #pragma unroll
        for (int j = 0; j < 8; ++j){
            v[j] = *(const uint*)(x0F + (size_t)s[j]*64 + off);
            if (eb + j >= e1) v[j] = 0u;
        }
        #pragma unroll
        for (int j = 0; j < 8; ++j){
            a01 += __builtin_amdgcn_cvt_pk_f32_fp8(v[j], false);
            a23 += __builtin_amdgcn_cvt_pk_f32_fp8(v[j], true);
        }
        if (t < 4){
            #pragma unroll
            for (int j = 0; j < 8; ++j){
                float cv = bf_lo((uint)covB[(size_t)s[j]*4 + t]);
                c += (eb + j < e1) ? cv : 0.f;
            }
        }
    }
    // combine qw pair (lanes l <-> l^16)
    a01.x += __shfl_xor(a01.x, 16); a01.y += __shfl_xor(a01.y, 16);
    a23.x += __shfl_xor(a23.x, 16); a23.y += __shfl_xor(a23.y, 16);
    c     += __shfl_xor(c, 16);
    if (h == 0){
        uint2 pk;
        pk.x = (uint)f2bf(a01.x) | ((uint)f2bf(a01.y) << 16);
        pk.y = (uint)f2bf(a23.x) | ((uint)f2bf(a23.y) << 16);
        #pragma unroll
        for (int b = 0; b < 4; ++b){
            float cb = __shfl(c, (l & 48) | b);   // qw-base lane + b holds batch-b cov sum
            uint2 o = pk;
            if (t == 15) o.y = (o.y & 0xffffu) | ((uint)f2bf(cb) << 16);  // col63 = cov agg
            *(uint2*)(&sAgg[(size_t)(nodeRow + b)*72 + t*4]) = o;
        }
    }
}

// ---------------- generic gather helpers: masked 8-chunk load + convert ----------------
__device__ __forceinline__ void load8(uint4 v[8], const uchar* __restrict__ xF,
                                      const int* __restrict__ csr_src,
                                      int eb, int e1, uint off){
    #pragma unroll
    for (int j = 0; j < 8; ++j){
        int ee = eb + j; if (ee >= e1) ee = e1 - 1;
        int s = csr_src[ee];
        v[j] = *(const uint4*)(xF + (size_t)s*256 + off);
    }
}
__device__ __forceinline__ void conv8(const uint4 v[8], int eb, int e1, f32x2 ac[8]){
    #pragma unroll
    for (int j = 0; j < 8; ++j){
        uint4 x = v[j];
        if (eb + j >= e1) x = (uint4){0u,0u,0u,0u};   // fp8 0x00 == 0.0
        ac[0] += __builtin_amdgcn_cvt_pk_f32_fp8(x.x, false);
        ac[1] += __builtin_amdgcn_cvt_pk_f32_fp8(x.x, true);
        ac[2] += __builtin_amdgcn_cvt_pk_f32_fp8(x.y, false);
        ac[3] += __builtin_amdgcn_cvt_pk_f32_fp8(x.y, true);
        ac[4] += __builtin_amdgcn_cvt_pk_f32_fp8(x.z, false);
        ac[5] += __builtin_amdgcn_cvt_pk_f32_fp8(x.z, true);
        ac[6] += __builtin_amdgcn_cvt_pk_f32_fp8(x.w, false);
        ac[7] += __builtin_amdgcn_cvt_pk_f32_fp8(x.w, true);
    }
}

// ---------------- generic gather: qw-pair per node, 8-deep chunks stride 16, 256B records ----------------
__device__ __forceinline__ void gather4q(const uchar* __restrict__ xF,
                                         const int* __restrict__ csr_src,
                                         int e0, int e1, int l,
                                         ushort* __restrict__ sAgg, int nodeRow){
    const int h = (l >> 4) & 1;         // which half of the qw pair
    const int t = l & 15;               // 16B group within the 256B record
    const uint off = (uint)(t*16);
    f32x2 ac[8];
    #pragma unroll
    for (int k = 0; k < 8; ++k) ac[k] = (f32x2){0.f,0.f};

    uint4 va[8], vb[8];
    int eb = e0 + 8*h;
    if (eb < e1){
        load8(va, xF, csr_src, eb, e1, off);
        while (true){
            int ebB = eb + 16;
            if (ebB >= e1){ conv8(va, eb, e1, ac); break; }
            load8(vb, xF, csr_src, ebB, e1, off);
            conv8(va, eb, e1, ac);
            int ebA = ebB + 16;
            if (ebA >= e1){ conv8(vb, ebB, e1, ac); break; }
            load8(va, xF, csr_src, ebA, e1, off);
            conv8(vb, ebB, e1, ac);
            eb = ebA;
        }
    }
    // combine qw pair (lanes l <-> l^16)
    #pragma unroll
    for (int k = 0; k < 8; ++k){
        ac[k].x += __shfl_xor(ac[k].x, 16);
        ac[k].y += __shfl_xor(ac[k].y, 16);
    }
    if (h == 0){
        // lane t owns record bytes 16t..16t+15: batch = t>>2, cols (t&3)*16 .. +15
        const int row = nodeRow + (t >> 2);
        const int c0  = (t & 3)*16;
        uint4 o0, o1;
        o0.x = (uint)f2bf(ac[0].x) | ((uint)f2bf(ac[0].y) << 16);
        o0.y = (uint)f2bf(ac[1].x) | ((uint)f2bf(ac[1].y) << 16);
        o0.z = (uint)f2bf(ac[2].x) | ((uint)f2bf(ac[2].y) << 16);
        o0.w = (uint)f2bf(ac[3].x) | ((uint)f2bf(ac[3].y) << 16);
        o1.x = (uint)f2bf(ac[4].x) | ((uint)f2bf(ac[4].y) << 16);
        o1.y = (uint)f2bf(ac[5].x) | ((uint)f2bf(ac[5].y) << 16);
        o1.z = (uint)f2bf(ac[6].x) | ((uint)f2bf(ac[6].y) << 16);
        o1.w = (uint)f2bf(ac[7].x) | ((uint)f2bf(ac[7].y) << 16);
        *(uint4*)(&sAgg[(size_t)row*72 + c0])     = o0;
        *(uint4*)(&sAgg[(size_t)row*72 + c0 + 8]) = o1;
    }
}

// ---------------- shared GRU core (32-row tile): staged LDS tiles -> x' (float) ----------------
__device__ __forceinline__ void gru_core(const ushort* sAgg, const ushort* sX,
                                         const ushort* __restrict__ wfb, const ushort* __restrict__ whhb,
                                         const float* __restrict__ bih, const float* __restrict__ bhh,
                                         int li, int q, int n0, float xv[2][4]){
    f32x4 Cr[2], Cz[2], Cxn[2], Chn[2];
    #pragma unroll
    for (int m = 0; m < 2; ++m){
        Cr[m]=(f32x4){0.f,0.f,0.f,0.f}; Cz[m]=(f32x4){0.f,0.f,0.f,0.f};
        Cxn[m]=(f32x4){0.f,0.f,0.f,0.f}; Chn[m]=(f32x4){0.f,0.f,0.f,0.f};
    }
    __builtin_amdgcn_s_setprio(1);
    #pragma unroll
    for (int ks = 0; ks < 4; ++ks){
        const ushort* wb = (ks < 2) ? wfb : whhb;
        const ushort* sT = (ks < 2) ? sAgg : sX;
        const int kb = (ks & 1)*32;
        bf16x8 Br = ldfrag(wb + (size_t)(n0 + li)*64 + kb + q*8);
        bf16x8 Bz = ldfrag(wb + (size_t)(64 + n0 + li)*64 + kb + q*8);
        bf16x8 Bn = ldfrag(wb + (size_t)(128 + n0 + li)*64 + kb + q*8);
        #pragma unroll
        for (int m = 0; m < 2; ++m){
            bf16x8 A = ldfrag(&sT[(m*16 + li)*72 + kb + q*8]);
            Cr[m] = MFMA(A, Br, Cr[m]);
            Cz[m] = MFMA(A, Bz, Cz[m]);
            if (ks < 2) Cxn[m] = MFMA(A, Bn, Cxn[m]);
            else        Chn[m] = MFMA(A, Bn, Chn[m]);
        }
    }
    __builtin_amdgcn_s_setprio(0);
    const int c = n0 + li;
    const float br_ = bih[c]     + bhh[c];
    const float bz_ = bih[64+c]  + bhh[64+c];
    const float bn_ = bih[128+c];
    const float bh_ = bhh[128+c];
    #pragma unroll
    for (int m = 0; m < 2; ++m){
        #pragma unroll
        for (int rg = 0; rg < 4; ++rg){
            int rl = m*16 + q*4 + rg;
            float r = sigm(Cr[m][rg] + br_);
            float z = sigm(Cz[m][rg] + bz_);
            float nng = tanh_f(Cxn[m][rg] + bn_ + r*(Chn[m][rg] + bh_));
            xv[m][rg] = (1.f - z)*nng + z*bfu(sX[rl*72 + c]);
        }
    }
}

// ---------------- coalesced state store via LDS transpose (32-row tile) ----------------
__device__ __forceinline__ void store_state(ushort* sAgg, uchar* sF8, int tx, int w, int li, int q,
                                            const float xv[2][4], int R0,
                                            ushort* __restrict__ xout, uchar* __restrict__ xFout){
    __syncthreads();                              // all gru_core LDS reads done
    const int c = 16*w + li;
    #pragma unroll
    for (int m = 0; m < 2; ++m)
        #pragma unroll
        for (int rg = 0; rg < 4; ++rg){
            int r = m*16 + q*4 + rg;
            sAgg[r*72 + c] = f2bf(xv[m][rg]);
            sF8[r*64 + c]  = f2fp8(xv[m][rg]);
        }
    __syncthreads();
    {                                             // bf16 state: 256 coalesced uint4 rows
        int r = tx >> 3, g = tx & 7;
        *(uint4*)(xout + (size_t)(R0 + r)*64 + g*8) = *(const uint4*)(&sAgg[r*72 + g*8]);
    }
    if (tx < 128){                                // fp8 state: 128 coalesced uint4 rows
        int r = tx >> 2, g = tx & 3;
        *(uint4*)(xFout + (size_t)(R0 + r)*64 + g*16) = *(const uint4*)(&sF8[r*64 + g*16]);
    }
}

// ---------------- fused GRU layer 0: gather0 + GRU ----------------
__global__ __launch_bounds__(256, 8) void k_gru0f(const uchar* __restrict__ x0F,
                                               const ushort* __restrict__ covB,
                                               const int* __restrict__ row_start,
                                               const int* __restrict__ csr_src,
                                               const ushort* __restrict__ x0I,
                                               const ushort* __restrict__ wfb, const ushort* __restrict__ whhb,
                                               const float* __restrict__ bih, const float* __restrict__ bhh,
                                               ushort* __restrict__ xout, uchar* __restrict__ xFout){
    __shared__ __align__(16) ushort sAgg[RPB*72];
    __shared__ __align__(16) ushort sX[RPB*72];
    __shared__ __align__(16) uchar  sF8[RPB*64];
    const int tx = threadIdx.x;
    const int l  = tx & 63, li = l & 15, q = l >> 4;
    const int w  = __builtin_amdgcn_readfirstlane(tx >> 6);
    const int R0 = blockIdx.x*RPB;
    const int nd = tx >> 5;                       // node 0..7 (2 per wave)
    const int d  = blockIdx.x*NPB + nd;
    const int e0 = row_start[d], e1 = row_start[d+1];

    {
        int r = tx >> 3, g = tx & 7;
        *(uint4*)(&sX[r*72 + g*8]) = *(const uint4*)(x0I + (size_t)(R0 + r)*64 + g*8);
    }
    gather0q(x0F, covB, csr_src, e0, e1, l, sAgg, nd*4);
    __syncthreads();

    float xv[2][4];
    gru_core(sAgg, sX, wfb, whhb, bih, bhh, li, q, 16*w, xv);
    store_state(sAgg, sF8, tx, w, li, q, xv, R0, xout, xFout);
}

// ---------------- fused GRU layer (1..3): gather + GRU ----------------
__global__ __launch_bounds__(256, 8) void k_gruFf(const uchar* __restrict__ xFin,
                                               const int* __restrict__ row_start,
                                               const int* __restrict__ csr_src,
                                               const ushort* __restrict__ xsrc,
                                               const ushort* __restrict__ wfb, const ushort* __restrict__ whhb,
                                               const float* __restrict__ bih, const float* __restrict__ bhh,
                                               ushort* __restrict__ xout, uchar* __restrict__ xFout){
    __shared__ __align__(16) ushort sAgg[RPB*72];
    __shared__ __align__(16) ushort sX[RPB*72];
    __shared__ __align__(16) uchar  sF8[RPB*64];
    const int tx = threadIdx.x;
    const int l  = tx & 63, li = l & 15, q = l >> 4;
    const int w  = __builtin_amdgcn_readfirstlane(tx >> 6);
    const int R0 = blockIdx.x*RPB;
    const int nd = tx >> 5;
    const int d  = blockIdx.x*NPB + nd;
    const int e0 = row_start[d], e1 = row_start[d+1];

    {
        int r = tx >> 3, g = tx & 7;
        *(uint4*)(&sX[r*72 + g*8]) = *(const uint4*)(xsrc + (size_t)(R0 + r)*64 + g*8);
    }
    gather4q(xFin, csr_src, e0, e1, l, sAgg, nd*4);
    __syncthreads();

    float xv[2][4];
    gru_core(sAgg, sX, wfb, whhb, bih, bhh, li, q, 16*w, xv);
    store_state(sAgg, sF8, tx, w, li, q, xv, R0, xout, xFout);
}

// ---------------- fused last layer: gather + GRU + attention ----------------
__global__ __launch_bounds__(256, 8) void k_gruLf(const uchar* __restrict__ xFin,
                                               const int* __restrict__ row_start,
                                               const int* __restrict__ csr_src,
                                               const ushort* __restrict__ xsrc,
                                               const ushort* __restrict__ wfb, const ushort* __restrict__ whhb,
                                               const float* __restrict__ bih, const float* __restrict__ bhh,
                                               const ushort* __restrict__ x0I,
                                               const ushort* __restrict__ aiwb, const float* __restrict__ aib,
                                               const ushort* __restrict__ ajwb, const float* __restrict__ ajb,
                                               float* __restrict__ pooled16){
    __shared__ __align__(16) ushort sAgg[RPB*72];
    __shared__ __align__(16) ushort sX[RPB*72];
    const int tx = threadIdx.x;
    const int l  = tx & 63, li = l & 15, q = l >> 4;
    const int w  = __builtin_amdgcn_readfirstlane(tx >> 6);
    const int R0 = blockIdx.x*RPB;
    const int nd = tx >> 5;
    const int d  = blockIdx.x*NPB + nd;
    const int e0 = row_start[d], e1 = row_start[d+1];

    {
        int r = tx >> 3, g = tx & 7;
        *(uint4*)(&sX[r*72 + g*8]) = *(const uint4*)(xsrc + (size_t)(R0 + r)*64 + g*8);
    }
    gather4q(xFin, csr_src, e0, e1, l, sAgg, nd*4);
    __syncthreads();

    float xv[2][4];
    gru_core(sAgg, sX, wfb, whhb, bih, bhh, li, q, 16*w, xv);
    __syncthreads();                              // all reads of sAgg/sX done

    // cat tile: x' -> sAgg (transpose from C-layout), x0 -> sX (coalesced)
    const int c = 16*w + li;
    #pragma unroll
    for (int m = 0; m < 2; ++m)
        #pragma unroll
        for (int rg = 0; rg < 4; ++rg)
            sAgg[(m*16 + q*4 + rg)*72 + c] = f2bf(xv[m][rg]);
    {
        int r = tx >> 3, g = tx & 7;
        *(uint4*)(&sX[r*72 + g*8]) = *(const uint4*)(x0I + (size_t)(R0 + r)*64 + g*8);
    }
    __syncthreads();

    f32x4 Ai[2][2], Aj[2][2];
    #pragma unroll
    for (int t = 0; t < 2; ++t)
        #pragma unroll
        for (int m = 0; m < 2; ++m){ Ai[t][m]=(f32x4){0.f,0.f,0.f,0.f}; Aj[t][m]=(f32x4){0.f,0.f,0.f,0.f}; }

    const int nb0 = 32*w;
    __builtin_amdgcn_s_setprio(1);
    #pragma unroll
    for (int ks = 0; ks < 4; ++ks){
        const ushort* sT = (ks < 2) ? sAgg : sX;
        const int kb = (ks & 1)*32;
        bf16x8 Bi[2], Bj[2];
        #pragma unroll
        for (int t = 0; t < 2; ++t){
            Bi[t] = ldfrag(aiwb + (size_t)(nb0 + 16*t + li)*128 + ks*32 + q*8);
            Bj[t] = ldfrag(ajwb + (size_t)(nb0 + 16*t + li)*128 + ks*32 + q*8);
        }
        #pragma unroll
        for (int m = 0; m < 2; ++m){
            bf16x8 A = ldfrag(&sT[(m*16 + li)*72 + kb + q*8]);
            #pragma unroll
            for (int t = 0; t < 2; ++t){
                Ai[t][m] = MFMA(A, Bi[t], Ai[t][m]);
                Aj[t][m] = MFMA(A, Bj[t], Aj[t][m]);
            }
        }
    }
    __builtin_amdgcn_s_setprio(0);

    float* pb = pooled16 + (size_t)(blockIdx.x & 15)*512;
    #pragma unroll
    for (int t = 0; t < 2; ++t){
        int cc = nb0 + 16*t + li;
        float bia = aib[cc], bja = ajb[cc];
        float vs[4] = {0.f, 0.f, 0.f, 0.f};
        #pragma unroll
        for (int m = 0; m < 2; ++m){
            #pragma unroll
            for (int rg = 0; rg < 4; ++rg){
                float s = sigm(Ai[t][m][rg] + bia);
                float a = Aj[t][m][rg] + bja;
                a = a > 0.f ? a : 0.f;
                vs[rg] += s*a;                    // batch == rg (interleaved rows)
            }
        }
        #pragma unroll
        for (int b = 0; b < 4; ++b){
            vs[b] += __shfl_xor(vs[b], 16);
            vs[b] += __shfl_xor(vs[b], 32);
        }
        if (l < 16){
            #pragma unroll
            for (int b = 0; b < 4; ++b) atomicAdd(&pb[b*128 + nb0 + 16*t + l], vs[b]);
        }
    }
}

// ---------------- final MLP + critic: one block per batch ----------------
__global__ void k_final(const float* __restrict__ pooled16, const float* __restrict__ mw,
                        const float* __restrict__ mb, const float* __restrict__ cw,
                        const float* __restrict__ cb, float* __restrict__ out){
    __shared__ float red[256];
    int t = threadIdx.x;
    int b = blockIdx.x;
    float acc = mb[t];
    #pragma unroll 4
    for (int k = 0; k < 128; ++k){
        float p = 0.f;
        #pragma unroll
        for (int kb = 0; kb < 16; ++kb) p += pooled16[kb*512 + b*128 + k];
        p = p > 0.f ? p : 0.f;
        acc = fmaf(p, mw[t*128 + k], acc);
    }
    float st = acc > 0.f ? acc : 0.f;
    red[t] = st * cw[t];
    __syncthreads();
    for (int off = 128; off > 0; off >>= 1){
        if (t < off) red[t] += red[t + off];
        __syncthreads();
    }
    if (t == 0) out[b] = red[0] + cb[0];
}

extern "C" void kernel_launch(void* const* d_in, const int* in_sizes, int n_in,
                              void* d_out, int out_size, void* d_ws, size_t ws_size,
                              hipStream_t stream) {
    const float* cov   = (const float*)d_in[0];
    const float* nodes = (const float*)d_in[1];
    const int*   edges = (const int*)d_in[2];
    const int*   c2l   = (const int*)d_in[3];
    const float* ggc   = (const float*)d_in[4];
    const float* wih   = (const float*)d_in[5];
    const float* whh   = (const float*)d_in[6];
    const float* bih   = (const float*)d_in[7];
    const float* bhh   = (const float*)d_in[8];
    const float* aiw   = (const float*)d_in[9];
    const float* aib   = (const float*)d_in[10];
    const float* ajw   = (const float*)d_in[11];
    const float* ajb   = (const float*)d_in[12];
    const float* mlpw  = (const float*)d_in[13];
    const float* mlpb  = (const float*)d_in[14];
    const float* cw    = (const float*)d_in[15];
    const float* cb    = (const float*)d_in[16];
    float* out = (float*)d_out;

    const size_t XSZ = (size_t)BN * 64;          // 12.8M elements
    float* ws = (float*)d_ws;
    float* pooled16 = ws;                        // 16*512 floats
    ushort* xS    = (ushort*)(pooled16 + 8192);  // bf16 interleaved state (in-place)
    ushort* x0I   = xS + XSZ;                    // bf16 interleaved x0
    ushort* aggx  = x0I + XSZ;                   // reused as xF ping buffer
    ushort* covB  = aggx + XSZ;                  // NN*4 per-batch cov
    ushort* whhb  = covB + (size_t)NN*4;         // 12288
    ushort* aiwb  = whhb + 12288;                // 16384
    ushort* ajwb  = aiwb + 16384;                // 16384
    ushort* wfb   = ajwb + 16384;                // 5*12288 fused ih weights
    uchar* xF     = (uchar*)(wfb + 61440);       // fp8 interleaved state, BN*64 bytes
    uchar* x0F    = xF + XSZ;                    // fp8 batch-invariant x0, NN*64 bytes
    int* cnt       = (int*)(x0F + (size_t)NN*64);
    int* tmp       = cnt + NN;
    int* bsum      = tmp + NN;
    int* boff      = bsum + 256;
    int* row_start = boff + 256;
    int* cursor    = row_start + (NN + 1);
    int* csr_src   = cursor + NN;

    hipMemsetAsync(cnt, 0, (size_t)NN*sizeof(int), stream);
    hipMemsetAsync(pooled16, 0, 8192*sizeof(float), stream);
    hipMemsetAsync(covB, 0, (size_t)NN*4*sizeof(ushort), stream);

    k_setup<<<HIST_NBLK + 416 + X0_NBLK, 256, 0, stream>>>(edges, cnt, wih, whh, aiw, ajw, ggc,
                                                           whhb, aiwb, ajwb, wfb,
                                                           nodes, x0I, x0F);
    k_scan1<<<SCAN_NBLK + COV_NBLK, 256, 0, stream>>>(cnt, tmp, bsum, cov, c2l, x0I, covB);
    k_scan3<<<SCAN_NBLK, 256, 0, stream>>>(tmp, bsum, row_start, cursor);
    k_fillcsr<<<(NE + 255)/256, 256, 0, stream>>>(edges, cursor, csr_src);

    // fp8 state ping-pong: layer i reads xFbuf[(i+1)&1], writes xFbuf[i&1].
    uchar* xFbuf[2] = { xF, (uchar*)aggx };

    for (int i = 0; i < NLAY; ++i){
        const ushort* wf = wfb + (size_t)i*12288;
        if (i == 0){
            k_gru0f<<<NT2, 256, 0, stream>>>(x0F, covB, row_start, csr_src, x0I,
                                             wf, whhb, bih, bhh, xS, xFbuf[0]);
        } else if (i < NLAY - 1){
            k_gruFf<<<NT2, 256, 0, stream>>>(xFbuf[(i+1)&1], row_start, csr_src, xS,
                                             wf, whhb, bih, bhh, xS, xFbuf[i&1]);
        } else {
            k_gruLf<<<NT2, 256, 0, stream>>>(xFbuf[(i+1)&1], row_start, csr_src, xS,
                                             wf, whhb, bih, bhh,
                                             x0I, aiwb, aib, ajwb, ajb, pooled16);
        }
    }

    k_final<<<NB, 256, 0, stream>>>(pooled16, mlpw, mlpb, cw, cb, out);
    (void)in_sizes; (void)n_in; (void)out_size; (void)ws_size;
}

// Round 7
// 579.517 us; speedup vs baseline: 1.6788x; 1.6788x over previous
//
#include <hip/hip_runtime.h>
#include <math.h>

#define NN 50000
#define NF 63
#define NE 800000
#define NL 10000
#define NB 4
#define NLAY 5
#define BN (NB*NN)                 // 200000 rows
#define RPB 32                     // rows per block
#define NPB 8                      // nodes per block
#define NT2 (BN/RPB)               // 6250 blocks
#define SCAN_NBLK ((NN+255)/256)   // 196
#define HIST_NBLK ((NE+255)/256)   // 3125
#define X0_NBLK ((BN*16)/256)      // 12500
#define COV_NBLK ((NB*NL+255)/256) // 157

using f32x4  = __attribute__((ext_vector_type(4))) float;
using f32x2  = __attribute__((ext_vector_type(2))) float;
using bf16x8 = __attribute__((ext_vector_type(8))) __bf16;

__device__ __forceinline__ float frcp(float x){ return __builtin_amdgcn_rcpf(x); }
__device__ __forceinline__ float sigm(float v){ return frcp(1.f + __expf(-v)); }
__device__ __forceinline__ float tanh_f(float v){ return fmaf(-2.f, frcp(__expf(2.f*v) + 1.f), 1.f); }

__device__ __forceinline__ ushort f2bf(float f){
    uint u = __builtin_bit_cast(uint, f);
    u += 0x7fffu + ((u >> 16) & 1u);
    return (ushort)(u >> 16);
}
__device__ __forceinline__ float bf_lo(uint v){ return __builtin_bit_cast(float, v << 16); }
__device__ __forceinline__ float bfu(ushort v){ return __builtin_bit_cast(float, ((uint)v) << 16); }

__device__ __forceinline__ uchar f2fp8(float v){
    int enc = __builtin_amdgcn_cvt_pk_fp8_f32(v, v, 0, false);
    return (uchar)(enc & 0xff);
}

__device__ __forceinline__ bf16x8 ldfrag(const ushort* p){
    uint4 v = *(const uint4*)p;
    return __builtin_bit_cast(bf16x8, v);
}
__device__ __forceinline__ f32x4 MFMA(bf16x8 a, bf16x8 b, f32x4 c){
    return __builtin_amdgcn_mfma_f32_16x16x32_bf16(a, b, c, 0, 0, 0);
}

// ---------------- hist + weight prep + x0 build (merged) ----------------
__global__ void k_setup(const int* __restrict__ edges, int* __restrict__ cnt,
                        const float* __restrict__ wih, const float* __restrict__ whh,
                        const float* __restrict__ aiw, const float* __restrict__ ajw,
                        const float* __restrict__ ggc,
                        ushort* __restrict__ whhb, ushort* __restrict__ aiwb,
                        ushort* __restrict__ ajwb, ushort* __restrict__ wfb,
                        const float* __restrict__ nodes, ushort* __restrict__ x0I,
                        uchar* __restrict__ x0F){
    int bid = blockIdx.x;
    if (bid < HIST_NBLK){
        int e = bid*256 + threadIdx.x;
        if (e < NE) atomicAdd(&cnt[edges[NE + e]], 1);
        return;
    }
    if (bid < HIST_NBLK + 416){
        int i = (bid - HIST_NBLK)*256 + threadIdx.x;   // 0..106495
        if (i < 12288)        whhb[i]        = f2bf(whh[i]);
        else if (i < 28672)   aiwb[i-12288]  = f2bf(aiw[i-12288]);
        else if (i < 45056)   ajwb[i-28672]  = f2bf(ajw[i-28672]);
        else if (i < 106496){
            int t = i - 45056;                         // 0..61439
            int lay = t / 12288;
            int rem = t % 12288;
            int n = rem >> 6, k = rem & 63;
            const float* W  = ggc + lay*4096 + k*64;
            const float* wr = wih + n*64;
            float s = 0.f;
            #pragma unroll 8
            for (int c = 0; c < 64; ++c) s = fmaf(W[c], wr[c], s);
            wfb[t] = f2bf(s);
        }
        return;
    }
    // x0 build: interleaved x0I (bf16) + batch-invariant x0F (fp8)
    int f = (bid - HIST_NBLK - 416)*256 + threadIdx.x; // 8B group index, BN*16 total
    int row = f >> 4, c4 = f & 15;
    int n = row % NN, b = row / NN;
    float v[4];
    #pragma unroll
    for (int i = 0; i < 4; ++i){
        int c = c4*4 + i;
        v[i] = (c < NF) ? nodes[(size_t)n*NF + c] : 0.f;
    }
    uint2 pk;
    pk.x = (uint)f2bf(v[0]) | ((uint)f2bf(v[1]) << 16);
    pk.y = (uint)f2bf(v[2]) | ((uint)f2bf(v[3]) << 16);
    *(uint2*)(x0I + ((size_t)n*4 + b)*64 + c4*4) = pk;
    if (b == 0){
        uint q = 0;
        q = (uint)__builtin_amdgcn_cvt_pk_fp8_f32(v[0], v[1], (int)q, false);
        q = (uint)__builtin_amdgcn_cvt_pk_fp8_f32(v[2], v[3], (int)q, true);
        *(uint*)(x0F + (size_t)n*64 + c4*4) = q;   // col63 stays 0 (v[3]=0 at c4=15)
    }
}

// scan1 + cov scatter (merged; cov blocks don't touch scan state)
__global__ void k_scan1(const int* __restrict__ cnt, int* __restrict__ tmp, int* __restrict__ bsum,
                        const float* __restrict__ cov, const int* __restrict__ c2l,
                        ushort* __restrict__ x0I, ushort* __restrict__ covB){
    if (blockIdx.x >= SCAN_NBLK){
        int i = (blockIdx.x - SCAN_NBLK)*256 + threadIdx.x;
        if (i < NB*NL){
            int b = i / NL, j = i % NL;
            int nd = c2l[j];
            ushort vb = f2bf(cov[i]);
            x0I[((size_t)nd*4 + b)*64 + 63] = vb;
            covB[(size_t)nd*4 + b] = vb;
        }
        return;
    }
    __shared__ int sh[256];
    int tx = threadIdx.x, i = blockIdx.x*256 + tx;
    int v = (i < NN) ? cnt[i] : 0;
    sh[tx] = v; __syncthreads();
    for (int off = 1; off < 256; off <<= 1){
        int u = (tx >= off) ? sh[tx-off] : 0;
        __syncthreads();
        sh[tx] += u;
        __syncthreads();
    }
    int incl = sh[tx];
    if (i < NN) tmp[i] = incl - v;
    if (tx == 255) bsum[blockIdx.x] = incl;
}

// scan of bsum done redundantly per block (merged scan2+scan3)
__global__ void k_scan3(const int* __restrict__ tmp, const int* __restrict__ bsum,
                        int* __restrict__ row_start, int* __restrict__ cursor){
    __shared__ int sh[256];
    int tx = threadIdx.x;
    int v = (tx < SCAN_NBLK) ? bsum[tx] : 0;
    sh[tx] = v; __syncthreads();
    for (int off = 1; off < 256; off <<= 1){
        int u = (tx >= off) ? sh[tx-off] : 0;
        __syncthreads();
        sh[tx] += u;
        __syncthreads();
    }
    int boff = sh[blockIdx.x] - bsum[blockIdx.x];   // exclusive prefix for this block
    int i = blockIdx.x*256 + tx;
    if (i < NN){
        int rs = tmp[i] + boff;
        row_start[i] = rs;
        cursor[i] = rs;
    }
    if (i == 0) row_start[NN] = NE;
}

__global__ void k_fillcsr(const int* __restrict__ edges, int* __restrict__ cursor, int* __restrict__ csr_src){
    int e = blockIdx.x*256 + threadIdx.x;
    if (e < NE){
        int d = edges[NE + e];
        int pos = atomicAdd(&cursor[d], 1);
        csr_src[pos] = edges[e];
    }
}

// ---------------- layer-0 gather: qw-pair per node, 8-deep chunks stride 16, 64B records + cov ----------------
__device__ __forceinline__ void gather0q(const uchar* __restrict__ x0F,
                                         const ushort* __restrict__ covB,
                                         const int* __restrict__ csr_src,
                                         int e0, int e1, int l,
                                         ushort* __restrict__ sAgg, int nodeRow){
    const int h = (l >> 4) & 1;         // which half of the qw pair
    const int t = l & 15;
    const uint off = (uint)(t*4);
    f32x2 a01 = (f32x2){0.f,0.f}, a23 = (f32x2){0.f,0.f};
    float c = 0.f;
    for (int eb = e0 + 8*h; eb < e1; eb += 16){
        int s[8];
        #pragma unroll
        for (int j = 0; j < 8; ++j){ int ee = eb + j; if (ee >= e1) ee = e1 - 1; s[j] = csr_src[ee]; }
        uint v[8];
        #pragma unroll
        for (int j = 0; j < 8; ++j){
            v[j] = *(const uint*)(x0F + (size_t)s[j]*64 + off);
            if (eb + j >= e1) v[j] = 0u;
        }
        #pragma unroll
        for (int j = 0; j < 8; ++j){
            a01 += __builtin_amdgcn_cvt_pk_f32_fp8(v[j], false);
            a23 += __builtin_amdgcn_cvt_pk_f32_fp8(v[j], true);
        }
        if (t < 4){
            #pragma unroll
            for (int j = 0; j < 8; ++j){
                float cv = bf_lo((uint)covB[(size_t)s[j]*4 + t]);
                c += (eb + j < e1) ? cv : 0.f;
            }
        }
    }
    // combine qw pair (lanes l <-> l^16)
    a01.x += __shfl_xor(a01.x, 16); a01.y += __shfl_xor(a01.y, 16);
    a23.x += __shfl_xor(a23.x, 16); a23.y += __shfl_xor(a23.y, 16);
    c     += __shfl_xor(c, 16);
    if (h == 0){
        uint2 pk;
        pk.x = (uint)f2bf(a01.x) | ((uint)f2bf(a01.y) << 16);
        pk.y = (uint)f2bf(a23.x) | ((uint)f2bf(a23.y) << 16);
        #pragma unroll
        for (int b = 0; b < 4; ++b){
            float cb = __shfl(c, (l & 48) | b);   // qw-base lane + b holds batch-b cov sum
            uint2 o = pk;
            if (t == 15) o.y = (o.y & 0xffffu) | ((uint)f2bf(cb) << 16);  // col63 = cov agg
            *(uint2*)(&sAgg[(size_t)(nodeRow + b)*72 + t*4]) = o;
        }
    }
}

// ---------------- generic gather helpers: masked 8-chunk load + convert ----------------
__device__ __forceinline__ void load8(uint4 v[8], const uchar* __restrict__ xF,
                                      const int* __restrict__ csr_src,
                                      int eb, int e1, uint off){
    #pragma unroll
    for (int j = 0; j < 8; ++j){
        int ee = eb + j; if (ee >= e1) ee = e1 - 1;
        int s = csr_src[ee];
        v[j] = *(const uint4*)(xF + (size_t)s*256 + off);
    }
}
__device__ __forceinline__ void conv8(const uint4 v[8], int eb, int e1, f32x2 ac[8]){
    #pragma unroll
    for (int j = 0; j < 8; ++j){
        uint4 x = v[j];
        if (eb + j >= e1) x = (uint4){0u,0u,0u,0u};   // fp8 0x00 == 0.0
        ac[0] += __builtin_amdgcn_cvt_pk_f32_fp8(x.x, false);
        ac[1] += __builtin_amdgcn_cvt_pk_f32_fp8(x.x, true);
        ac[2] += __builtin_amdgcn_cvt_pk_f32_fp8(x.y, false);
        ac[3] += __builtin_amdgcn_cvt_pk_f32_fp8(x.y, true);
        ac[4] += __builtin_amdgcn_cvt_pk_f32_fp8(x.z, false);
        ac[5] += __builtin_amdgcn_cvt_pk_f32_fp8(x.z, true);
        ac[6] += __builtin_amdgcn_cvt_pk_f32_fp8(x.w, false);
        ac[7] += __builtin_amdgcn_cvt_pk_f32_fp8(x.w, true);
    }
}

// ---------------- generic gather: qw-pair per node, single-buffer 8-deep chunks stride 16 ----------------
__device__ __forceinline__ void gather4q(const uchar* __restrict__ xF,
                                         const int* __restrict__ csr_src,
                                         int e0, int e1, int l,
                                         ushort* __restrict__ sAgg, int nodeRow){
    const int h = (l >> 4) & 1;         // which half of the qw pair
    const int t = l & 15;               // 16B group within the 256B record
    const uint off = (uint)(t*16);
    f32x2 ac[8];
    #pragma unroll
    for (int k = 0; k < 8; ++k) ac[k] = (f32x2){0.f,0.f};

    for (int eb = e0 + 8*h; eb < e1; eb += 16){
        uint4 v[8];
        load8(v, xF, csr_src, eb, e1, off);
        conv8(v, eb, e1, ac);
    }
    // combine qw pair (lanes l <-> l^16)
    #pragma unroll
    for (int k = 0; k < 8; ++k){
        ac[k].x += __shfl_xor(ac[k].x, 16);
        ac[k].y += __shfl_xor(ac[k].y, 16);
    }
    if (h == 0){
        // lane t owns record bytes 16t..16t+15: batch = t>>2, cols (t&3)*16 .. +15
        const int row = nodeRow + (t >> 2);
        const int c0  = (t & 3)*16;
        uint4 o0, o1;
        o0.x = (uint)f2bf(ac[0].x) | ((uint)f2bf(ac[0].y) << 16);
        o0.y = (uint)f2bf(ac[1].x) | ((uint)f2bf(ac[1].y) << 16);
        o0.z = (uint)f2bf(ac[2].x) | ((uint)f2bf(ac[2].y) << 16);
        o0.w = (uint)f2bf(ac[3].x) | ((uint)f2bf(ac[3].y) << 16);
        o1.x = (uint)f2bf(ac[4].x) | ((uint)f2bf(ac[4].y) << 16);
        o1.y = (uint)f2bf(ac[5].x) | ((uint)f2bf(ac[5].y) << 16);
        o1.z = (uint)f2bf(ac[6].x) | ((uint)f2bf(ac[6].y) << 16);
        o1.w = (uint)f2bf(ac[7].x) | ((uint)f2bf(ac[7].y) << 16);
        *(uint4*)(&sAgg[(size_t)row*72 + c0])     = o0;
        *(uint4*)(&sAgg[(size_t)row*72 + c0 + 8]) = o1;
    }
}

// ---------------- shared GRU core (32-row tile): staged LDS tiles -> x' (float) ----------------
__device__ __forceinline__ void gru_core(const ushort* sAgg, const ushort* sX,
                                         const ushort* __restrict__ wfb, const ushort* __restrict__ whhb,
                                         const float* __restrict__ bih, const float* __restrict__ bhh,
                                         int li, int q, int n0, float xv[2][4]){
    f32x4 Cr[2], Cz[2], Cxn[2], Chn[2];
    #pragma unroll
    for (int m = 0; m < 2; ++m){
        Cr[m]=(f32x4){0.f,0.f,0.f,0.f}; Cz[m]=(f32x4){0.f,0.f,0.f,0.f};
        Cxn[m]=(f32x4){0.f,0.f,0.f,0.f}; Chn[m]=(f32x4){0.f,0.f,0.f,0.f};
    }
    __builtin_amdgcn_s_setprio(1);
    #pragma unroll
    for (int ks = 0; ks < 4; ++ks){
        const ushort* wb = (ks < 2) ? wfb : whhb;
        const ushort* sT = (ks < 2) ? sAgg : sX;
        const int kb = (ks & 1)*32;
        bf16x8 Br = ldfrag(wb + (size_t)(n0 + li)*64 + kb + q*8);
        bf16x8 Bz = ldfrag(wb + (size_t)(64 + n0 + li)*64 + kb + q*8);
        bf16x8 Bn = ldfrag(wb + (size_t)(128 + n0 + li)*64 + kb + q*8);
        #pragma unroll
        for (int m = 0; m < 2; ++m){
            bf16x8 A = ldfrag(&sT[(m*16 + li)*72 + kb + q*8]);
            Cr[m] = MFMA(A, Br, Cr[m]);
            Cz[m] = MFMA(A, Bz, Cz[m]);
            if (ks < 2) Cxn[m] = MFMA(A, Bn, Cxn[m]);
            else        Chn[m] = MFMA(A, Bn, Chn[m]);
        }
    }
    __builtin_amdgcn_s_setprio(0);
    const int c = n0 + li;
    const float br_ = bih[c]     + bhh[c];
    const float bz_ = bih[64+c]  + bhh[64+c];
    const float bn_ = bih[128+c];
    const float bh_ = bhh[128+c];
    #pragma unroll
    for (int m = 0; m < 2; ++m){
        #pragma unroll
        for (int rg = 0; rg < 4; ++rg){
            int rl = m*16 + q*4 + rg;
            float r = sigm(Cr[m][rg] + br_);
            float z = sigm(Cz[m][rg] + bz_);
            float nng = tanh_f(Cxn[m][rg] + bn_ + r*(Chn[m][rg] + bh_));
            xv[m][rg] = (1.f - z)*nng + z*bfu(sX[rl*72 + c]);
        }
    }
}

// ---------------- coalesced state store via LDS transpose (32-row tile) ----------------
__device__ __forceinline__ void store_state(ushort* sAgg, uchar* sF8, int tx, int w, int li, int q,
                                            const float xv[2][4], int R0,
                                            ushort* __restrict__ xout, uchar* __restrict__ xFout){
    __syncthreads();                              // all gru_core LDS reads done
    const int c = 16*w + li;
    #pragma unroll
    for (int m = 0; m < 2; ++m)
        #pragma unroll
        for (int rg = 0; rg < 4; ++rg){
            int r = m*16 + q*4 + rg;
            sAgg[r*72 + c] = f2bf(xv[m][rg]);
            sF8[r*64 + c]  = f2fp8(xv[m][rg]);
        }
    __syncthreads();
    {                                             // bf16 state: 256 coalesced uint4 rows
        int r = tx >> 3, g = tx & 7;
        *(uint4*)(xout + (size_t)(R0 + r)*64 + g*8) = *(const uint4*)(&sAgg[r*72 + g*8]);
    }
    if (tx < 128){                                // fp8 state: 128 coalesced uint4 rows
        int r = tx >> 2, g = tx & 3;
        *(uint4*)(xFout + (size_t)(R0 + r)*64 + g*16) = *(const uint4*)(&sF8[r*64 + g*16]);
    }
}

// ---------------- fused GRU layer 0: gather0 + GRU ----------------
__global__ __launch_bounds__(256, 4) void k_gru0f(const uchar* __restrict__ x0F,
                                               const ushort* __restrict__ covB,
                                               const int* __restrict__ row_start,
                                               const int* __restrict__ csr_src,
                                               const ushort* __restrict__ x0I,
                                               const ushort* __restrict__ wfb, const ushort* __restrict__ whhb,
                                               const float* __restrict__ bih, const float* __restrict__ bhh,
                                               ushort* __restrict__ xout, uchar* __restrict__ xFout){
    __shared__ __align__(16) ushort sAgg[RPB*72];
    __shared__ __align__(16) ushort sX[RPB*72];
    __shared__ __align__(16) uchar  sF8[RPB*64];
    const int tx = threadIdx.x;
    const int l  = tx & 63, li = l & 15, q = l >> 4;
    const int w  = __builtin_amdgcn_readfirstlane(tx >> 6);
    const int R0 = blockIdx.x*RPB;
    const int nd = tx >> 5;                       // node 0..7 (2 per wave)
    const int d  = blockIdx.x*NPB + nd;
    const int e0 = row_start[d], e1 = row_start[d+1];

    {
        int r = tx >> 3, g = tx & 7;
        *(uint4*)(&sX[r*72 + g*8]) = *(const uint4*)(x0I + (size_t)(R0 + r)*64 + g*8);
    }
    gather0q(x0F, covB, csr_src, e0, e1, l, sAgg, nd*4);
    __syncthreads();

    float xv[2][4];
    gru_core(sAgg, sX, wfb, whhb, bih, bhh, li, q, 16*w, xv);
    store_state(sAgg, sF8, tx, w, li, q, xv, R0, xout, xFout);
}

// ---------------- fused GRU layer (1..3): gather + GRU ----------------
__global__ __launch_bounds__(256, 4) void k_gruFf(const uchar* __restrict__ xFin,
                                               const int* __restrict__ row_start,
                                               const int* __restrict__ csr_src,
                                               const ushort* __restrict__ xsrc,
                                               const ushort* __restrict__ wfb, const ushort* __restrict__ whhb,
                                               const float* __restrict__ bih, const float* __restrict__ bhh,
                                               ushort* __restrict__ xout, uchar* __restrict__ xFout){
    __shared__ __align__(16) ushort sAgg[RPB*72];
    __shared__ __align__(16) ushort sX[RPB*72];
    __shared__ __align__(16) uchar  sF8[RPB*64];
    const int tx = threadIdx.x;
    const int l  = tx & 63, li = l & 15, q = l >> 4;
    const int w  = __builtin_amdgcn_readfirstlane(tx >> 6);
    const int R0 = blockIdx.x*RPB;
    const int nd = tx >> 5;
    const int d  = blockIdx.x*NPB + nd;
    const int e0 = row_start[d], e1 = row_start[d+1];

    {
        int r = tx >> 3, g = tx & 7;
        *(uint4*)(&sX[r*72 + g*8]) = *(const uint4*)(xsrc + (size_t)(R0 + r)*64 + g*8);
    }
    gather4q(xFin, csr_src, e0, e1, l, sAgg, nd*4);
    __syncthreads();

    float xv[2][4];
    gru_core(sAgg, sX, wfb, whhb, bih, bhh, li, q, 16*w, xv);
    store_state(sAgg, sF8, tx, w, li, q, xv, R0, xout, xFout);
}

// ---------------- fused last layer: gather + GRU + attention ----------------
__global__ __launch_bounds__(256, 4) void k_gruLf(const uchar* __restrict__ xFin,
                                               const int* __restrict__ row_start,
                                               const int* __restrict__ csr_src,
                                               const ushort* __restrict__ xsrc,
                                               const ushort* __restrict__ wfb, const ushort* __restrict__ whhb,
                                               const float* __restrict__ bih, const float* __restrict__ bhh,
                                               const ushort* __restrict__ x0I,
                                               const ushort* __restrict__ aiwb, const float* __restrict__ aib,
                                               const ushort* __restrict__ ajwb, const float* __restrict__ ajb,
                                               float* __restrict__ pooled16){
    __shared__ __align__(16) ushort sAgg[RPB*72];
    __shared__ __align__(16) ushort sX[RPB*72];
    const int tx = threadIdx.x;
    const int l  = tx & 63, li = l & 15, q = l >> 4;
    const int w  = __builtin_amdgcn_readfirstlane(tx >> 6);
    const int R0 = blockIdx.x*RPB;
    const int nd = tx >> 5;
    const int d  = blockIdx.x*NPB + nd;
    const int e0 = row_start[d], e1 = row_start[d+1];

    {
        int r = tx >> 3, g = tx & 7;
        *(uint4*)(&sX[r*72 + g*8]) = *(const uint4*)(xsrc + (size_t)(R0 + r)*64 + g*8);
    }
    gather4q(xFin, csr_src, e0, e1, l, sAgg, nd*4);
    __syncthreads();

    float xv[2][4];
    gru_core(sAgg, sX, wfb, whhb, bih, bhh, li, q, 16*w, xv);
    __syncthreads();                              // all reads of sAgg/sX done

    // cat tile: x' -> sAgg (transpose from C-layout), x0 -> sX (coalesced)
    const int c = 16*w + li;
    #pragma unroll
    for (int m = 0; m < 2; ++m)
        #pragma unroll
        for (int rg = 0; rg < 4; ++rg)
            sAgg[(m*16 + q*4 + rg)*72 + c] = f2bf(xv[m][rg]);
    {
        int r = tx >> 3, g = tx & 7;
        *(uint4*)(&sX[r*72 + g*8]) = *(const uint4*)(x0I + (size_t)(R0 + r)*64 + g*8);
    }
    __syncthreads();

    f32x4 Ai[2][2], Aj[2][2];
    #pragma unroll
    for (int t = 0; t < 2; ++t)
        #pragma unroll
        for (int m = 0; m < 2; ++m){ Ai[t][m]=(f32x4){0.f,0.f,0.f,0.f}; Aj[t][m]=(f32x4){0.f,0.f,0.f,0.f}; }

    const int nb0 = 32*w;
    __builtin_amdgcn_s_setprio(1);
    #pragma unroll
    for (int ks = 0; ks < 4; ++ks){
        const ushort* sT = (ks < 2) ? sAgg : sX;
        const int kb = (ks & 1)*32;
        bf16x8 Bi[2], Bj[2];
        #pragma unroll
        for (int t = 0; t < 2; ++t){
            Bi[t] = ldfrag(aiwb + (size_t)(nb0 + 16*t + li)*128 + ks*32 + q*8);
            Bj[t] = ldfrag(ajwb + (size_t)(nb0 + 16*t + li)*128 + ks*32 + q*8);
        }
        #pragma unroll
        for (int m = 0; m < 2; ++m){
            bf16x8 A = ldfrag(&sT[(m*16 + li)*72 + kb + q*8]);
            #pragma unroll
            for (int t = 0; t < 2; ++t){
                Ai[t][m] = MFMA(A, Bi[t], Ai[t][m]);
                Aj[t][m] = MFMA(A, Bj[t], Aj[t][m]);
            }
        }
    }
    __builtin_amdgcn_s_setprio(0);

    float* pb = pooled16 + (size_t)(blockIdx.x & 15)*512;
    #pragma unroll
    for (int t = 0; t < 2; ++t){
        int cc = nb0 + 16*t + li;
        float bia = aib[cc], bja = ajb[cc];
        float vs[4] = {0.f, 0.f, 0.f, 0.f};
        #pragma unroll
        for (int m = 0; m < 2; ++m){
            #pragma unroll
            for (int rg = 0; rg < 4; ++rg){
                float s = sigm(Ai[t][m][rg] + bia);
                float a = Aj[t][m][rg] + bja;
                a = a > 0.f ? a : 0.f;
                vs[rg] += s*a;                    // batch == rg (interleaved rows)
            }
        }
        #pragma unroll
        for (int b = 0; b < 4; ++b){
            vs[b] += __shfl_xor(vs[b], 16);
            vs[b] += __shfl_xor(vs[b], 32);
        }
        if (l < 16){
            #pragma unroll
            for (int b = 0; b < 4; ++b) atomicAdd(&pb[b*128 + nb0 + 16*t + l], vs[b]);
        }
    }
}

// ---------------- final MLP + critic: one block per batch ----------------
__global__ void k_final(const float* __restrict__ pooled16, const float* __restrict__ mw,
                        const float* __restrict__ mb, const float* __restrict__ cw,
                        const float* __restrict__ cb, float* __restrict__ out){
    __shared__ float red[256];
    int t = threadIdx.x;
    int b = blockIdx.x;
    float acc = mb[t];
    #pragma unroll 4
    for (int k = 0; k < 128; ++k){
        float p = 0.f;
        #pragma unroll
        for (int kb = 0; kb < 16; ++kb) p += pooled16[kb*512 + b*128 + k];
        p = p > 0.f ? p : 0.f;
        acc = fmaf(p, mw[t*128 + k], acc);
    }
    float st = acc > 0.f ? acc : 0.f;
    red[t] = st * cw[t];
    __syncthreads();
    for (int off = 128; off > 0; off >>= 1){
        if (t < off) red[t] += red[t + off];
        __syncthreads();
    }
    if (t == 0) out[b] = red[0] + cb[0];
}

extern "C" void kernel_launch(void* const* d_in, const int* in_sizes, int n_in,
                              void* d_out, int out_size, void* d_ws, size_t ws_size,
                              hipStream_t stream) {
    const float* cov   = (const float*)d_in[0];
    const float* nodes = (const float*)d_in[1];
    const int*   edges = (const int*)d_in[2];
    const int*   c2l   = (const int*)d_in[3];
    const float* ggc   = (const float*)d_in[4];
    const float* wih   = (const float*)d_in[5];
    const float* whh   = (const float*)d_in[6];
    const float* bih   = (const float*)d_in[7];
    const float* bhh   = (const float*)d_in[8];
    const float* aiw   = (const float*)d_in[9];
    const float* aib   = (const float*)d_in[10];
    const float* ajw   = (const float*)d_in[11];
    const float* ajb   = (const float*)d_in[12];
    const float* mlpw  = (const float*)d_in[13];
    const float* mlpb  = (const float*)d_in[14];
    const float* cw    = (const float*)d_in[15];
    const float* cb    = (const float*)d_in[16];
    float* out = (float*)d_out;

    const size_t XSZ = (size_t)BN * 64;          // 12.8M elements
    float* ws = (float*)d_ws;
    float* pooled16 = ws;                        // 16*512 floats
    ushort* xS    = (ushort*)(pooled16 + 8192);  // bf16 interleaved state (in-place)
    ushort* x0I   = xS + XSZ;                    // bf16 interleaved x0
    ushort* aggx  = x0I + XSZ;                   // reused as xF ping buffer
    ushort* covB  = aggx + XSZ;                  // NN*4 per-batch cov
    ushort* whhb  = covB + (size_t)NN*4;         // 12288
    ushort* aiwb  = whhb + 12288;                // 16384
    ushort* ajwb  = aiwb + 16384;                // 16384
    ushort* wfb   = ajwb + 16384;                // 5*12288 fused ih weights
    uchar* xF     = (uchar*)(wfb + 61440);       // fp8 interleaved state, BN*64 bytes
    uchar* x0F    = xF + XSZ;                    // fp8 batch-invariant x0, NN*64 bytes
    int* cnt       = (int*)(x0F + (size_t)NN*64);
    int* tmp       = cnt + NN;
    int* bsum      = tmp + NN;
    int* boff      = bsum + 256;
    int* row_start = boff + 256;
    int* cursor    = row_start + (NN + 1);
    int* csr_src   = cursor + NN;

    hipMemsetAsync(cnt, 0, (size_t)NN*sizeof(int), stream);
    hipMemsetAsync(pooled16, 0, 8192*sizeof(float), stream);
    hipMemsetAsync(covB, 0, (size_t)NN*4*sizeof(ushort), stream);

    k_setup<<<HIST_NBLK + 416 + X0_NBLK, 256, 0, stream>>>(edges, cnt, wih, whh, aiw, ajw, ggc,
                                                           whhb, aiwb, ajwb, wfb,
                                                           nodes, x0I, x0F);
    k_scan1<<<SCAN_NBLK + COV_NBLK, 256, 0, stream>>>(cnt, tmp, bsum, cov, c2l, x0I, covB);
    k_scan3<<<SCAN_NBLK, 256, 0, stream>>>(tmp, bsum, row_start, cursor);
    k_fillcsr<<<(NE + 255)/256, 256, 0, stream>>>(edges, cursor, csr_src);

    // fp8 state ping-pong: layer i reads xFbuf[(i+1)&1], writes xFbuf[i&1].
    uchar* xFbuf[2] = { xF, (uchar*)aggx };

    for (int i = 0; i < NLAY; ++i){
        const ushort* wf = wfb + (size_t)i*12288;
        if (i == 0){
            k_gru0f<<<NT2, 256, 0, stream>>>(x0F, covB, row_start, csr_src, x0I,
                                             wf, whhb, bih, bhh, xS, xFbuf[0]);
        } else if (i < NLAY - 1){
            k_gruFf<<<NT2, 256, 0, stream>>>(xFbuf[(i+1)&1], row_start, csr_src, xS,
                                             wf, whhb, bih, bhh, xS, xFbuf[i&1]);
        } else {
            k_gruLf<<<NT2, 256, 0, stream>>>(xFbuf[(i+1)&1], row_start, csr_src, xS,
                                             wf, whhb, bih, bhh,
                                             x0I, aiwb, aib, ajwb, ajb, pooled16);
        }
    }

    k_final<<<NB, 256, 0, stream>>>(pooled16, mlpw, mlpb, cw, cb, out);
    (void)in_sizes; (void)n_in; (void)out_size; (void)ws_size;
}

// Round 8
// 477.804 us; speedup vs baseline: 2.0362x; 1.2129x over previous
//
#include <hip/hip_runtime.h>
#include <math.h>

#define NN 50000
#define NF 63
#define NE 800000
#define NL 10000
#define NB 4
#define NLAY 5
#define BN (NB*NN)                 // 200000 rows
#define NTILES (BN/64)             // 3125 blocks (64 rows = 16 nodes each)
#define SCAN_NBLK ((NN+255)/256)   // 196
#define HIST_NBLK ((NE+255)/256)   // 3125
#define X0_NBLK ((BN*16)/256)      // 12500
#define COV_NBLK ((NB*NL+255)/256) // 157

using f32x4  = __attribute__((ext_vector_type(4))) float;
using f32x2  = __attribute__((ext_vector_type(2))) float;
using bf16x8 = __attribute__((ext_vector_type(8))) __bf16;

__device__ __forceinline__ float frcp(float x){ return __builtin_amdgcn_rcpf(x); }
__device__ __forceinline__ float sigm(float v){ return frcp(1.f + __expf(-v)); }
__device__ __forceinline__ float tanh_f(float v){ return fmaf(-2.f, frcp(__expf(2.f*v) + 1.f), 1.f); }

__device__ __forceinline__ ushort f2bf(float f){
    uint u = __builtin_bit_cast(uint, f);
    u += 0x7fffu + ((u >> 16) & 1u);
    return (ushort)(u >> 16);
}
__device__ __forceinline__ float bf_lo(uint v){ return __builtin_bit_cast(float, v << 16); }
__device__ __forceinline__ float bf_hi(uint v){ return __builtin_bit_cast(float, v & 0xffff0000u); }
__device__ __forceinline__ float bfu(ushort v){ return __builtin_bit_cast(float, ((uint)v) << 16); }

__device__ __forceinline__ bf16x8 ldfrag(const ushort* p){
    uint4 v = *(const uint4*)p;
    return __builtin_bit_cast(bf16x8, v);
}
__device__ __forceinline__ f32x4 MFMA(bf16x8 a, bf16x8 b, f32x4 c){
    return __builtin_amdgcn_mfma_f32_16x16x32_bf16(a, b, c, 0, 0, 0);
}

// ---------------- hist + weight prep + x0 build (merged) ----------------
__global__ void k_setup(const int* __restrict__ edges, int* __restrict__ cnt,
                        const float* __restrict__ wih, const float* __restrict__ whh,
                        const float* __restrict__ aiw, const float* __restrict__ ajw,
                        const float* __restrict__ ggc,
                        ushort* __restrict__ whhb, ushort* __restrict__ aiwb,
                        ushort* __restrict__ ajwb, ushort* __restrict__ wfb,
                        const float* __restrict__ nodes, ushort* __restrict__ x0I,
                        uchar* __restrict__ x0F){
    int bid = blockIdx.x;
    if (bid < HIST_NBLK){
        int e = bid*256 + threadIdx.x;
        if (e < NE) atomicAdd(&cnt[edges[NE + e]], 1);
        return;
    }
    if (bid < HIST_NBLK + 416){
        int i = (bid - HIST_NBLK)*256 + threadIdx.x;   // 0..106495
        if (i < 12288)        whhb[i]        = f2bf(whh[i]);
        else if (i < 28672)   aiwb[i-12288]  = f2bf(aiw[i-12288]);
        else if (i < 45056)   ajwb[i-28672]  = f2bf(ajw[i-28672]);
        else if (i < 106496){
            int t = i - 45056;                         // 0..61439
            int lay = t / 12288;
            int rem = t % 12288;
            int n = rem >> 6, k = rem & 63;
            const float* W  = ggc + lay*4096 + k*64;
            const float* wr = wih + n*64;
            float s = 0.f;
            #pragma unroll 8
            for (int c = 0; c < 64; ++c) s = fmaf(W[c], wr[c], s);
            wfb[t] = f2bf(s);
        }
        return;
    }
    // x0 build: interleaved x0I (bf16) + batch-invariant x0F (fp8)
    int f = (bid - HIST_NBLK - 416)*256 + threadIdx.x; // 8B group index, BN*16 total
    int row = f >> 4, c4 = f & 15;
    int n = row % NN, b = row / NN;
    float v[4];
    #pragma unroll
    for (int i = 0; i < 4; ++i){
        int c = c4*4 + i;
        v[i] = (c < NF) ? nodes[(size_t)n*NF + c] : 0.f;
    }
    uint2 pk;
    pk.x = (uint)f2bf(v[0]) | ((uint)f2bf(v[1]) << 16);
    pk.y = (uint)f2bf(v[2]) | ((uint)f2bf(v[3]) << 16);
    *(uint2*)(x0I + ((size_t)n*4 + b)*64 + c4*4) = pk;
    if (b == 0){
        uint q = 0;
        q = (uint)__builtin_amdgcn_cvt_pk_fp8_f32(v[0], v[1], (int)q, false);
        q = (uint)__builtin_amdgcn_cvt_pk_fp8_f32(v[2], v[3], (int)q, true);
        *(uint*)(x0F + (size_t)n*64 + c4*4) = q;   // col63 stays 0 (v[3]=0 at c4=15)
    }
}

// scan1 + cov scatter (merged; cov blocks don't touch scan state)
__global__ void k_scan1(const int* __restrict__ cnt, int* __restrict__ tmp, int* __restrict__ bsum,
                        const float* __restrict__ cov, const int* __restrict__ c2l,
                        ushort* __restrict__ x0I, ushort* __restrict__ covB){
    if (blockIdx.x >= SCAN_NBLK){
        int i = (blockIdx.x - SCAN_NBLK)*256 + threadIdx.x;
        if (i < NB*NL){
            int b = i / NL, j = i % NL;
            int nd = c2l[j];
            ushort vb = f2bf(cov[i]);
            x0I[((size_t)nd*4 + b)*64 + 63] = vb;
            covB[(size_t)nd*4 + b] = vb;
        }
        return;
    }
    __shared__ int sh[256];
    int tx = threadIdx.x, i = blockIdx.x*256 + tx;
    int v = (i < NN) ? cnt[i] : 0;
    sh[tx] = v; __syncthreads();
    for (int off = 1; off < 256; off <<= 1){
        int u = (tx >= off) ? sh[tx-off] : 0;
        __syncthreads();
        sh[tx] += u;
        __syncthreads();
    }
    int incl = sh[tx];
    if (i < NN) tmp[i] = incl - v;
    if (tx == 255) bsum[blockIdx.x] = incl;
}

// scan of bsum done redundantly per block (merged scan2+scan3)
__global__ void k_scan3(const int* __restrict__ tmp, const int* __restrict__ bsum,
                        int* __restrict__ row_start, int* __restrict__ cursor){
    __shared__ int sh[256];
    int tx = threadIdx.x;
    int v = (tx < SCAN_NBLK) ? bsum[tx] : 0;
    sh[tx] = v; __syncthreads();
    for (int off = 1; off < 256; off <<= 1){
        int u = (tx >= off) ? sh[tx-off] : 0;
        __syncthreads();
        sh[tx] += u;
        __syncthreads();
    }
    int boff = sh[blockIdx.x] - bsum[blockIdx.x];   // exclusive prefix for this block
    int i = blockIdx.x*256 + tx;
    if (i < NN){
        int rs = tmp[i] + boff;
        row_start[i] = rs;
        cursor[i] = rs;
    }
    if (i == 0) row_start[NN] = NE;
}

__global__ void k_fillcsr(const int* __restrict__ edges, int* __restrict__ cursor, int* __restrict__ csr_src){
    int e = blockIdx.x*256 + threadIdx.x;
    if (e < NE){
        int d = edges[NE + e];
        int pos = atomicAdd(&cursor[d], 1);
        csr_src[pos] = edges[e];
    }
}

// ---------------- fused layer-0 gather: quarter-wave per node, 16-deep, 64B records + cov ----------------
__device__ __forceinline__ void gather0q(const uchar* __restrict__ x0F,
                                         const ushort* __restrict__ covB,
                                         const int* __restrict__ row_start,
                                         const int* __restrict__ csr_src,
                                         int d0, int l, ushort* __restrict__ sAgg,
                                         int rbase){
    const int qn = l >> 4, t = l & 15;
    const uint off = (uint)(t*4);
    const int d = d0 + qn;
    const int e0 = row_start[d], e1 = row_start[d+1];
    f32x2 a01 = (f32x2){0.f,0.f}, a23 = (f32x2){0.f,0.f};
    float c = 0.f;
    int e = e0;
    for (; e + 16 <= e1; e += 16){
        int s[16];
        #pragma unroll
        for (int j = 0; j < 16; ++j) s[j] = csr_src[e + j];
        uint v[16];
        #pragma unroll
        for (int j = 0; j < 16; ++j) v[j] = *(const uint*)(x0F + (size_t)s[j]*64 + off);
        #pragma unroll
        for (int j = 0; j < 16; ++j){
            a01 += __builtin_amdgcn_cvt_pk_f32_fp8(v[j], false);
            a23 += __builtin_amdgcn_cvt_pk_f32_fp8(v[j], true);
        }
        if (t < 4){
            #pragma unroll
            for (int j = 0; j < 16; ++j) c += bf_lo((uint)covB[(size_t)s[j]*4 + t]);
        }
    }
    if (e < e1){                        // one masked 16-wide tail
        int s[16];
        #pragma unroll
        for (int j = 0; j < 16; ++j){ int ee = e + j; if (ee >= e1) ee = e1 - 1; s[j] = csr_src[ee]; }
        uint v[16];
        #pragma unroll
        for (int j = 0; j < 16; ++j){
            v[j] = *(const uint*)(x0F + (size_t)s[j]*64 + off);
            if (e + j >= e1) v[j] = 0u;
        }
        #pragma unroll
        for (int j = 0; j < 16; ++j){
            a01 += __builtin_amdgcn_cvt_pk_f32_fp8(v[j], false);
            a23 += __builtin_amdgcn_cvt_pk_f32_fp8(v[j], true);
        }
        if (t < 4){
            #pragma unroll
            for (int j = 0; j < 16; ++j){
                float cv = bf_lo((uint)covB[(size_t)s[j]*4 + t]);
                c += (e + j < e1) ? cv : 0.f;
            }
        }
    }
    uint2 pk;
    pk.x = (uint)f2bf(a01.x) | ((uint)f2bf(a01.y) << 16);
    pk.y = (uint)f2bf(a23.x) | ((uint)f2bf(a23.y) << 16);
    #pragma unroll
    for (int b = 0; b < 4; ++b){
        float cb = __shfl(c, (l & 48) | b);       // lane qn*16+b holds batch-b cov sum
        uint2 o = pk;
        if (t == 15) o.y = (o.y & 0xffffu) | ((uint)f2bf(cb) << 16);  // col63 = cov agg
        *(uint2*)(&sAgg[(size_t)(rbase + qn*4 + b)*72 + t*4]) = o;
    }
}

// ---------------- fused generic gather: quarter-wave per node, 16-deep, 256B fp8 records ----------------
__device__ __forceinline__ void gather4q(const uchar* __restrict__ xF,
                                         const int* __restrict__ row_start,
                                         const int* __restrict__ csr_src,
                                         int d0, int l, ushort* __restrict__ sAgg,
                                         int rbase){
    const int qn = l >> 4;              // which of the 4 nodes this quarter-wave owns
    const int t  = l & 15;              // 16B group within the 256B record
    const uint off = (uint)(t*16);
    const int d = d0 + qn;
    const int e0 = row_start[d], e1 = row_start[d+1];
    f32x2 ac[8];
    #pragma unroll
    for (int k = 0; k < 8; ++k) ac[k] = (f32x2){0.f,0.f};

    int e = e0;
    for (; e + 16 <= e1; e += 16){      // 16 edges in flight per node
        int s[16];
        #pragma unroll
        for (int j = 0; j < 16; ++j) s[j] = csr_src[e + j];
        uint4 v[16];
        #pragma unroll
        for (int j = 0; j < 16; ++j) v[j] = *(const uint4*)(xF + (size_t)s[j]*256 + off);
        #pragma unroll
        for (int j = 0; j < 16; ++j){
            ac[0] += __builtin_amdgcn_cvt_pk_f32_fp8(v[j].x, false);
            ac[1] += __builtin_amdgcn_cvt_pk_f32_fp8(v[j].x, true);
            ac[2] += __builtin_amdgcn_cvt_pk_f32_fp8(v[j].y, false);
            ac[3] += __builtin_amdgcn_cvt_pk_f32_fp8(v[j].y, true);
            ac[4] += __builtin_amdgcn_cvt_pk_f32_fp8(v[j].z, false);
            ac[5] += __builtin_amdgcn_cvt_pk_f32_fp8(v[j].z, true);
            ac[6] += __builtin_amdgcn_cvt_pk_f32_fp8(v[j].w, false);
            ac[7] += __builtin_amdgcn_cvt_pk_f32_fp8(v[j].w, true);
        }
    }
    if (e < e1){                        // one masked 16-wide tail (dup loads hit L1)
        int s[16];
        #pragma unroll
        for (int j = 0; j < 16; ++j){ int ee = e + j; if (ee >= e1) ee = e1 - 1; s[j] = csr_src[ee]; }
        uint4 v[16];
        #pragma unroll
        for (int j = 0; j < 16; ++j){
            v[j] = *(const uint4*)(xF + (size_t)s[j]*256 + off);
            if (e + j >= e1) v[j] = (uint4){0u,0u,0u,0u};   // fp8 0x00 == 0.0
        }
        #pragma unroll
        for (int j = 0; j < 16; ++j){
            ac[0] += __builtin_amdgcn_cvt_pk_f32_fp8(v[j].x, false);
            ac[1] += __builtin_amdgcn_cvt_pk_f32_fp8(v[j].x, true);
            ac[2] += __builtin_amdgcn_cvt_pk_f32_fp8(v[j].y, false);
            ac[3] += __builtin_amdgcn_cvt_pk_f32_fp8(v[j].y, true);
            ac[4] += __builtin_amdgcn_cvt_pk_f32_fp8(v[j].z, false);
            ac[5] += __builtin_amdgcn_cvt_pk_f32_fp8(v[j].z, true);
            ac[6] += __builtin_amdgcn_cvt_pk_f32_fp8(v[j].w, false);
            ac[7] += __builtin_amdgcn_cvt_pk_f32_fp8(v[j].w, true);
        }
    }

    // lane t owns record bytes 16t..16t+15: batch = t>>2, cols (t&3)*16 .. +15
    const int row = rbase + qn*4 + (t >> 2);
    const int c0  = (t & 3)*16;
    uint4 o0, o1;
    o0.x = (uint)f2bf(ac[0].x) | ((uint)f2bf(ac[0].y) << 16);
    o0.y = (uint)f2bf(ac[1].x) | ((uint)f2bf(ac[1].y) << 16);
    o0.z = (uint)f2bf(ac[2].x) | ((uint)f2bf(ac[2].y) << 16);
    o0.w = (uint)f2bf(ac[3].x) | ((uint)f2bf(ac[3].y) << 16);
    o1.x = (uint)f2bf(ac[4].x) | ((uint)f2bf(ac[4].y) << 16);
    o1.y = (uint)f2bf(ac[5].x) | ((uint)f2bf(ac[5].y) << 16);
    o1.z = (uint)f2bf(ac[6].x) | ((uint)f2bf(ac[6].y) << 16);
    o1.w = (uint)f2bf(ac[7].x) | ((uint)f2bf(ac[7].y) << 16);
    *(uint4*)(&sAgg[(size_t)row*72 + c0])     = o0;
    *(uint4*)(&sAgg[(size_t)row*72 + c0 + 8]) = o1;
}

// ---------------- shared GRU core: staged LDS tiles -> x' (float) ----------------
__device__ __forceinline__ void gru_core(const ushort* sAgg, const ushort* sX,
                                         const ushort* __restrict__ wfb, const ushort* __restrict__ whhb,
                                         const float* __restrict__ bih, const float* __restrict__ bhh,
                                         int li, int q, int n0, float xv[4][4]){
    f32x4 Cr[4], Cz[4], Cxn[4], Chn[4];
    #pragma unroll
    for (int m = 0; m < 4; ++m){
        Cr[m]=(f32x4){0.f,0.f,0.f,0.f}; Cz[m]=(f32x4){0.f,0.f,0.f,0.f};
        Cxn[m]=(f32x4){0.f,0.f,0.f,0.f}; Chn[m]=(f32x4){0.f,0.f,0.f,0.f};
    }
    __builtin_amdgcn_s_setprio(1);
    #pragma unroll
    for (int ks = 0; ks < 4; ++ks){
        const ushort* wb = (ks < 2) ? wfb : whhb;
        const ushort* sT = (ks < 2) ? sAgg : sX;
        const int kb = (ks & 1)*32;
        bf16x8 Br = ldfrag(wb + (size_t)(n0 + li)*64 + kb + q*8);
        bf16x8 Bz = ldfrag(wb + (size_t)(64 + n0 + li)*64 + kb + q*8);
        bf16x8 Bn = ldfrag(wb + (size_t)(128 + n0 + li)*64 + kb + q*8);
        #pragma unroll
        for (int m = 0; m < 4; ++m){
            bf16x8 A = ldfrag(&sT[(m*16 + li)*72 + kb + q*8]);
            Cr[m] = MFMA(A, Br, Cr[m]);
            Cz[m] = MFMA(A, Bz, Cz[m]);
            if (ks < 2) Cxn[m] = MFMA(A, Bn, Cxn[m]);
            else        Chn[m] = MFMA(A, Bn, Chn[m]);
        }
    }
    __builtin_amdgcn_s_setprio(0);
    const int c = n0 + li;
    const float br_ = bih[c]     + bhh[c];
    const float bz_ = bih[64+c]  + bhh[64+c];
    const float bn_ = bih[128+c];
    const float bh_ = bhh[128+c];
    #pragma unroll
    for (int m = 0; m < 4; ++m){
        #pragma unroll
        for (int rg = 0; rg < 4; ++rg){
            int rl = m*16 + q*4 + rg;
            float r = sigm(Cr[m][rg] + br_);
            float z = sigm(Cz[m][rg] + bz_);
            float nng = tanh_f(Cxn[m][rg] + bn_ + r*(Chn[m][rg] + bh_));
            xv[m][rg] = (1.f - z)*nng + z*bfu(sX[rl*72 + c]);
        }
    }
}

// ---------------- coalesced state store via LDS transpose (reuses sAgg) ----------------
__device__ __forceinline__ void store_state(ushort* sAgg, int tx, int w, int li, int q,
                                            const float xv[4][4], int R0,
                                            ushort* __restrict__ xout, uchar* __restrict__ xFout){
    __syncthreads();                              // all gru_core LDS reads done
    const int c = 16*w + li;
    #pragma unroll
    for (int m = 0; m < 4; ++m)
        #pragma unroll
        for (int rg = 0; rg < 4; ++rg)
            sAgg[(m*16 + q*4 + rg)*72 + c] = f2bf(xv[m][rg]);
    __syncthreads();
    #pragma unroll
    for (int it = 0; it < 2; ++it){               // bf16 state: coalesced uint4 rows
        int idx = it*256 + tx, r = idx >> 3, g = idx & 7;
        *(uint4*)(xout + (size_t)(R0 + r)*64 + g*8) = *(const uint4*)(&sAgg[r*72 + g*8]);
    }
    {                                             // fp8 state: 16 cols/thread, coalesced uint4
        int r = tx >> 2, g = tx & 3;
        const ushort* src = &sAgg[r*72 + g*16];
        uint4 a = *(const uint4*)src;
        uint4 b = *(const uint4*)(src + 8);
        uint4 o; uint qd;
        qd = (uint)__builtin_amdgcn_cvt_pk_fp8_f32(bf_lo(a.x), bf_hi(a.x), 0, false);
        qd = (uint)__builtin_amdgcn_cvt_pk_fp8_f32(bf_lo(a.y), bf_hi(a.y), (int)qd, true);
        o.x = qd;
        qd = (uint)__builtin_amdgcn_cvt_pk_fp8_f32(bf_lo(a.z), bf_hi(a.z), 0, false);
        qd = (uint)__builtin_amdgcn_cvt_pk_fp8_f32(bf_lo(a.w), bf_hi(a.w), (int)qd, true);
        o.y = qd;
        qd = (uint)__builtin_amdgcn_cvt_pk_fp8_f32(bf_lo(b.x), bf_hi(b.x), 0, false);
        qd = (uint)__builtin_amdgcn_cvt_pk_fp8_f32(bf_lo(b.y), bf_hi(b.y), (int)qd, true);
        o.z = qd;
        qd = (uint)__builtin_amdgcn_cvt_pk_fp8_f32(bf_lo(b.z), bf_hi(b.z), 0, false);
        qd = (uint)__builtin_amdgcn_cvt_pk_fp8_f32(bf_lo(b.w), bf_hi(b.w), (int)qd, true);
        o.w = qd;
        *(uint4*)(xFout + (size_t)(R0 + r)*64 + g*16) = o;
    }
}

// ---------------- fused GRU layer 0: gather0 + GRU ----------------
__global__ __launch_bounds__(256, 4) void k_gru0f(const uchar* __restrict__ x0F,
                                               const ushort* __restrict__ covB,
                                               const int* __restrict__ row_start,
                                               const int* __restrict__ csr_src,
                                               const ushort* __restrict__ x0I,
                                               const ushort* __restrict__ wfb, const ushort* __restrict__ whhb,
                                               const float* __restrict__ bih, const float* __restrict__ bhh,
                                               ushort* __restrict__ xout, uchar* __restrict__ xFout){
    __shared__ __align__(16) ushort sAgg[64*72];
    __shared__ __align__(16) ushort sX[64*72];
    const int tx = threadIdx.x;
    const int l  = tx & 63, li = l & 15, q = l >> 4;
    const int w  = __builtin_amdgcn_readfirstlane(tx >> 6);
    const int R0 = blockIdx.x*64;

    #pragma unroll
    for (int it = 0; it < 2; ++it){
        int idx = it*256 + tx, r = idx >> 3, g = idx & 7;
        *(uint4*)(&sX[r*72 + g*8]) = *(const uint4*)(x0I + (size_t)(R0 + r)*64 + g*8);
    }
    gather0q(x0F, covB, row_start, csr_src, blockIdx.x*16 + w*4, l, sAgg, w*16);
    __syncthreads();

    float xv[4][4];
    gru_core(sAgg, sX, wfb, whhb, bih, bhh, li, q, 16*w, xv);
    store_state(sAgg, tx, w, li, q, xv, R0, xout, xFout);
}

// ---------------- fused GRU layer (1..3): gather + GRU ----------------
__global__ __launch_bounds__(256, 4) void k_gruFf(const uchar* __restrict__ xFin,
                                               const int* __restrict__ row_start,
                                               const int* __restrict__ csr_src,
                                               const ushort* __restrict__ xsrc,
                                               const ushort* __restrict__ wfb, const ushort* __restrict__ whhb,
                                               const float* __restrict__ bih, const float* __restrict__ bhh,
                                               ushort* __restrict__ xout, uchar* __restrict__ xFout){
    __shared__ __align__(16) ushort sAgg[64*72];
    __shared__ __align__(16) ushort sX[64*72];
    const int tx = threadIdx.x;
    const int l  = tx & 63, li = l & 15, q = l >> 4;
    const int w  = __builtin_amdgcn_readfirstlane(tx >> 6);
    const int R0 = blockIdx.x*64;

    #pragma unroll
    for (int it = 0; it < 2; ++it){
        int idx = it*256 + tx, r = idx >> 3, g = idx & 7;
        *(uint4*)(&sX[r*72 + g*8]) = *(const uint4*)(xsrc + (size_t)(R0 + r)*64 + g*8);
    }
    gather4q(xFin, row_start, csr_src, blockIdx.x*16 + w*4, l, sAgg, w*16);
    __syncthreads();

    float xv[4][4];
    gru_core(sAgg, sX, wfb, whhb, bih, bhh, li, q, 16*w, xv);
    store_state(sAgg, tx, w, li, q, xv, R0, xout, xFout);
}

// ---------------- fused last layer: gather + GRU + attention ----------------
__global__ __launch_bounds__(256, 4) void k_gruLf(const uchar* __restrict__ xFin,
                                               const int* __restrict__ row_start,
                                               const int* __restrict__ csr_src,
                                               const ushort* __restrict__ xsrc,
                                               const ushort* __restrict__ wfb, const ushort* __restrict__ whhb,
                                               const float* __restrict__ bih, const float* __restrict__ bhh,
                                               const ushort* __restrict__ x0I,
                                               const ushort* __restrict__ aiwb, const float* __restrict__ aib,
                                               const ushort* __restrict__ ajwb, const float* __restrict__ ajb,
                                               float* __restrict__ pooled16){
    __shared__ __align__(16) ushort sAgg[64*72];
    __shared__ __align__(16) ushort sX[64*72];
    const int tx = threadIdx.x;
    const int l  = tx & 63, li = l & 15, q = l >> 4;
    const int w  = __builtin_amdgcn_readfirstlane(tx >> 6);
    const int R0 = blockIdx.x*64;

    #pragma unroll
    for (int it = 0; it < 2; ++it){
        int idx = it*256 + tx, r = idx >> 3, g = idx & 7;
        *(uint4*)(&sX[r*72 + g*8]) = *(const uint4*)(xsrc + (size_t)(R0 + r)*64 + g*8);
    }
    gather4q(xFin, row_start, csr_src, blockIdx.x*16 + w*4, l, sAgg, w*16);
    __syncthreads();

    float xv[4][4];
    gru_core(sAgg, sX, wfb, whhb, bih, bhh, li, q, 16*w, xv);
    __syncthreads();                              // all reads of sAgg/sX done

    // cat tile: x' -> sAgg (transpose from C-layout), x0 -> sX (coalesced)
    const int c = 16*w + li;
    #pragma unroll
    for (int m = 0; m < 4; ++m)
        #pragma unroll
        for (int rg = 0; rg < 4; ++rg)
            sAgg[(m*16 + q*4 + rg)*72 + c] = f2bf(xv[m][rg]);
    #pragma unroll
    for (int it = 0; it < 2; ++it){
        int idx = it*256 + tx, r = idx >> 3, g = idx & 7;
        *(uint4*)(&sX[r*72 + g*8]) = *(const uint4*)(x0I + (size_t)(R0 + r)*64 + g*8);
    }
    __syncthreads();

    f32x4 Ai[2][4], Aj[2][4];
    #pragma unroll
    for (int t = 0; t < 2; ++t)
        #pragma unroll
        for (int m = 0; m < 4; ++m){ Ai[t][m]=(f32x4){0.f,0.f,0.f,0.f}; Aj[t][m]=(f32x4){0.f,0.f,0.f,0.f}; }

    const int nb0 = 32*w;
    __builtin_amdgcn_s_setprio(1);
    #pragma unroll
    for (int ks = 0; ks < 4; ++ks){
        const ushort* sT = (ks < 2) ? sAgg : sX;
        const int kb = (ks & 1)*32;
        bf16x8 Bi[2], Bj[2];
        #pragma unroll
        for (int t = 0; t < 2; ++t){
            Bi[t] = ldfrag(aiwb + (size_t)(nb0 + 16*t + li)*128 + ks*32 + q*8);
            Bj[t] = ldfrag(ajwb + (size_t)(nb0 + 16*t + li)*128 + ks*32 + q*8);
        }
        #pragma unroll
        for (int m = 0; m < 4; ++m){
            bf16x8 A = ldfrag(&sT[(m*16 + li)*72 + kb + q*8]);
            #pragma unroll
            for (int t = 0; t < 2; ++t){
                Ai[t][m] = MFMA(A, Bi[t], Ai[t][m]);
                Aj[t][m] = MFMA(A, Bj[t], Aj[t][m]);
            }
        }
    }
    __builtin_amdgcn_s_setprio(0);

    float* pb = pooled16 + (size_t)(blockIdx.x & 15)*512;
    #pragma unroll
    for (int t = 0; t < 2; ++t){
        int cc = nb0 + 16*t + li;
        float bia = aib[cc], bja = ajb[cc];
        float vs[4] = {0.f, 0.f, 0.f, 0.f};
        #pragma unroll
        for (int m = 0; m < 4; ++m){
            #pragma unroll
            for (int rg = 0; rg < 4; ++rg){
                float s = sigm(Ai[t][m][rg] + bia);
                float a = Aj[t][m][rg] + bja;
                a = a > 0.f ? a : 0.f;
                vs[rg] += s*a;                    // batch == rg (interleaved rows)
            }
        }
        #pragma unroll
        for (int b = 0; b < 4; ++b){
            vs[b] += __shfl_xor(vs[b], 16);
            vs[b] += __shfl_xor(vs[b], 32);
        }
        if (l < 16){
            #pragma unroll
            for (int b = 0; b < 4; ++b) atomicAdd(&pb[b*128 + nb0 + 16*t + l], vs[b]);
        }
    }
}

// ---------------- final MLP + critic: one block per batch, LDS-staged pooled ----------------
__global__ void k_final(const float* __restrict__ pooled16, const float* __restrict__ mw,
                        const float* __restrict__ mb, const float* __restrict__ cw,
                        const float* __restrict__ cb, float* __restrict__ out){
    __shared__ float sp[128];
    __shared__ float red[256];
    int t = threadIdx.x;
    int b = blockIdx.x;
    if (t < 128){                                 // 16-way buffer reduce + ReLU once
        float p = 0.f;
        #pragma unroll
        for (int kb = 0; kb < 16; ++kb) p += pooled16[kb*512 + b*128 + t];
        sp[t] = p > 0.f ? p : 0.f;
    }
    __syncthreads();
    float acc = mb[t];
    #pragma unroll 8
    for (int k = 0; k < 128; ++k)
        acc = fmaf(sp[k], mw[t*128 + k], acc);
    float st = acc > 0.f ? acc : 0.f;
    red[t] = st * cw[t];
    __syncthreads();
    for (int off = 128; off > 0; off >>= 1){
        if (t < off) red[t] += red[t + off];
        __syncthreads();
    }
    if (t == 0) out[b] = red[0] + cb[0];
}

extern "C" void kernel_launch(void* const* d_in, const int* in_sizes, int n_in,
                              void* d_out, int out_size, void* d_ws, size_t ws_size,
                              hipStream_t stream) {
    const float* cov   = (const float*)d_in[0];
    const float* nodes = (const float*)d_in[1];
    const int*   edges = (const int*)d_in[2];
    const int*   c2l   = (const int*)d_in[3];
    const float* ggc   = (const float*)d_in[4];
    const float* wih   = (const float*)d_in[5];
    const float* whh   = (const float*)d_in[6];
    const float* bih   = (const float*)d_in[7];
    const float* bhh   = (const float*)d_in[8];
    const float* aiw   = (const float*)d_in[9];
    const float* aib   = (const float*)d_in[10];
    const float* ajw   = (const float*)d_in[11];
    const float* ajb   = (const float*)d_in[12];
    const float* mlpw  = (const float*)d_in[13];
    const float* mlpb  = (const float*)d_in[14];
    const float* cw    = (const float*)d_in[15];
    const float* cb    = (const float*)d_in[16];
    float* out = (float*)d_out;

    const size_t XSZ = (size_t)BN * 64;          // 12.8M elements
    float* ws = (float*)d_ws;
    float* pooled16 = ws;                        // 16*512 floats
    ushort* xS    = (ushort*)(pooled16 + 8192);  // bf16 interleaved state (in-place)
    ushort* x0I   = xS + XSZ;                    // bf16 interleaved x0
    ushort* aggx  = x0I + XSZ;                   // reused as xF ping buffer
    ushort* covB  = aggx + XSZ;                  // NN*4 per-batch cov
    ushort* whhb  = covB + (size_t)NN*4;         // 12288
    ushort* aiwb  = whhb + 12288;                // 16384
    ushort* ajwb  = aiwb + 16384;                // 16384
    ushort* wfb   = ajwb + 16384;                // 5*12288 fused ih weights
    uchar* xF     = (uchar*)(wfb + 61440);       // fp8 interleaved state, BN*64 bytes
    uchar* x0F    = xF + XSZ;                    // fp8 batch-invariant x0, NN*64 bytes
    int* cnt       = (int*)(x0F + (size_t)NN*64);
    int* tmp       = cnt + NN;
    int* bsum      = tmp + NN;
    int* boff      = bsum + 256;
    int* row_start = boff + 256;
    int* cursor    = row_start + (NN + 1);
    int* csr_src   = cursor + NN;

    hipMemsetAsync(cnt, 0, (size_t)NN*sizeof(int), stream);
    hipMemsetAsync(pooled16, 0, 8192*sizeof(float), stream);
    hipMemsetAsync(covB, 0, (size_t)NN*4*sizeof(ushort), stream);

    k_setup<<<HIST_NBLK + 416 + X0_NBLK, 256, 0, stream>>>(edges, cnt, wih, whh, aiw, ajw, ggc,
                                                           whhb, aiwb, ajwb, wfb,
                                                           nodes, x0I, x0F);
    k_scan1<<<SCAN_NBLK + COV_NBLK, 256, 0, stream>>>(cnt, tmp, bsum, cov, c2l, x0I, covB);
    k_scan3<<<SCAN_NBLK, 256, 0, stream>>>(tmp, bsum, row_start, cursor);
    k_fillcsr<<<(NE + 255)/256, 256, 0, stream>>>(edges, cursor, csr_src);

    // fp8 state ping-pong: layer i reads xFbuf[(i+1)&1], writes xFbuf[i&1].
    uchar* xFbuf[2] = { xF, (uchar*)aggx };

    for (int i = 0; i < NLAY; ++i){
        const ushort* wf = wfb + (size_t)i*12288;
        if (i == 0){
            k_gru0f<<<NTILES, 256, 0, stream>>>(x0F, covB, row_start, csr_src, x0I,
                                                wf, whhb, bih, bhh, xS, xFbuf[0]);
        } else if (i < NLAY - 1){
            k_gruFf<<<NTILES, 256, 0, stream>>>(xFbuf[(i+1)&1], row_start, csr_src, xS,
                                                wf, whhb, bih, bhh, xS, xFbuf[i&1]);
        } else {
            k_gruLf<<<NTILES, 256, 0, stream>>>(xFbuf[(i+1)&1], row_start, csr_src, xS,
                                                wf, whhb, bih, bhh,
                                                x0I, aiwb, aib, ajwb, ajb, pooled16);
        }
    }

    k_final<<<NB, 256, 0, stream>>>(pooled16, mlpw, mlpb, cw, cb, out);
    (void)in_sizes; (void)n_in; (void)out_size; (void)ws_size;
}